// Round 1
// baseline (18.443 us; speedup 1.0000x reference)
//
#include <hip/hip_runtime.h>

// DocumentBertScoringLoss: loss = MSE + MR + SIM over B=8192 fp32 vectors.
// Key simplification: MR term = mean over all (m,n) of max(0, 0.1 - |p_m - p_n|)
// (r*dp == |dp| when dp!=0; == 0 when dp==0, so correct_output never matters).

#define B_N 8192
#define NX 32          // m-chunks (256 threads each -> 32*256 = 8192 rows)
#define NY 32          // n-chunks (8192/32 = 256 n's per block, staged in LDS)
#define THREADS 256
#define CHUNK (B_N / NY)   // 256

__device__ __forceinline__ float block_reduce_sum(float v, float* sbuf) {
    // 64-lane wave reduce, then cross-wave via LDS.
    #pragma unroll
    for (int off = 32; off > 0; off >>= 1)
        v += __shfl_down(v, off, 64);
    const int lane = threadIdx.x & 63;
    const int wave = threadIdx.x >> 6;
    if (lane == 0) sbuf[wave] = v;
    __syncthreads();
    float r;
    if (threadIdx.x == 0) {
        float s = 0.f;
        #pragma unroll
        for (int w = 0; w < THREADS / 64; ++w) s += sbuf[w];
        sbuf[0] = s;
    }
    __syncthreads();
    r = sbuf[0];
    __syncthreads();   // safe reuse of sbuf by caller
    return r;
}

__global__ void __launch_bounds__(THREADS)
pairwise_mr_kernel(const float* __restrict__ p, float* __restrict__ partial) {
    __shared__ float s_p[CHUNK];
    __shared__ float sbuf[THREADS / 64];

    const int m = blockIdx.x * THREADS + threadIdx.x;   // this thread's row
    const int n0 = blockIdx.y * CHUNK;                  // this block's n-chunk

    s_p[threadIdx.x] = p[n0 + threadIdx.x];             // CHUNK == THREADS
    __syncthreads();

    const float pm = p[m];
    float acc = 0.f;
    #pragma unroll 8
    for (int j = 0; j < CHUNK; ++j) {
        const float d = pm - s_p[j];                    // broadcast LDS read
        acc += fmaxf(0.f, 0.1f - fabsf(d));
    }

    const float s = block_reduce_sum(acc, sbuf);
    if (threadIdx.x == 0)
        partial[blockIdx.y * NX + blockIdx.x] = s;      // fully overwritten each call
}

__global__ void __launch_bounds__(THREADS)
finalize_kernel(const float* __restrict__ p, const float* __restrict__ g,
                const float* __restrict__ partial, float* __restrict__ out) {
    __shared__ float sbuf[THREADS / 64];

    // 1) sum pairwise partials
    float mr_sum = 0.f;
    for (int i = threadIdx.x; i < NX * NY; i += THREADS) mr_sum += partial[i];

    // 2) O(B) reductions: sq-diff, dot, |p|^2, |g|^2
    float sq = 0.f, dot = 0.f, npp = 0.f, ngg = 0.f;
    for (int i = threadIdx.x; i < B_N; i += THREADS) {
        const float pv = p[i], gv = g[i];
        const float d = pv - gv;
        sq  += d * d;
        dot += pv * gv;
        npp += pv * pv;
        ngg += gv * gv;
    }

    mr_sum = block_reduce_sum(mr_sum, sbuf);
    sq     = block_reduce_sum(sq, sbuf);
    dot    = block_reduce_sum(dot, sbuf);
    npp    = block_reduce_sum(npp, sbuf);
    ngg    = block_reduce_sum(ngg, sbuf);

    if (threadIdx.x == 0) {
        const float mse = sq / (float)B_N;
        const float mr  = mr_sum / ((float)B_N * (float)B_N);
        const float denom = fmaxf(sqrtf(npp) * sqrtf(ngg), 1e-8f);
        const float sim = 1.f - dot / denom;
        out[0] = mse + mr + sim;   // alpha = beta = gamma = 1
    }
}

extern "C" void kernel_launch(void* const* d_in, const int* in_sizes, int n_in,
                              void* d_out, int out_size, void* d_ws, size_t ws_size,
                              hipStream_t stream) {
    const float* p = (const float*)d_in[0];
    const float* g = (const float*)d_in[1];
    float* partial = (float*)d_ws;     // NX*NY = 1024 floats = 4 KiB
    float* out = (float*)d_out;

    dim3 grid(NX, NY);
    pairwise_mr_kernel<<<grid, THREADS, 0, stream>>>(p, partial);
    finalize_kernel<<<1, THREADS, 0, stream>>>(p, g, partial, out);
}